// Round 8
// baseline (295.134 us; speedup 1.0000x reference)
//
#include <hip/hip_runtime.h>
#include <hip/hip_bf16.h>

// Butterfly structure (BASE=3, FACTOR=0, n=27):
//   mask[s,t] != 0  iff  floor(s1/3)==floor(t1/3) && floor(s2/3)==floor(t2/3),
//   s = 27*s1 + s2.  81 groups g=(G1,G2); group members: 81*G1 + 27*i + 3*G2 + j.
//   attn packed: attn[g*81 + ls*9 + lt], g = 9*G1+G2, ls/lt = 3i+j.
// Dtypes: inputs fp32, output fp32.
//
// Measured history (mlp kernel):
//   r0 LDS-stage:            88-92 us   r4 direct shallow: ~90 us
//   r5 direct 8-deep burst:  86.8 us    r6 all-coalesced:  85.4-88 us
//   r7 LDS dbuf + reg-stage: 86.6-90.7 us
//   r1/r2 persistent lockstep global_load_lds: 253 us, 4.2x traffic. Dead end.
// KEY: r7 compiled to VGPR=44 (intended pipeline needs >80) and r5 to 80
// (burst needs >100) -> hipcc SANK the prefetch loads to save registers,
// collapsing every source-level pipeline into sequential load-wait-compute.
// All six variants executed the same no-overlap schedule: ~1100 cy/row =
// 570 HBM + ~500 VALU/LDS, serial => 86 us. Overlapped floor ~45-50 us.
// This round: named double-buffer register chunks + sched_barrier(0x7)
// (ALU crosses, VMEM pinned) after each prefetch so loads CANNOT sink.
// Verification signature: VGPR_Count ~100-128 means the pipeline is real.

__device__ __forceinline__ float gelu_f(float v) {
    // tanh-form gelu; |err| < ~7e-4, threshold 1.44e-2 (measured absmax 3.9e-3).
    float u2 = v * v;
    float z = -1.5957691216f * v * fmaf(0.044715f, u2, 1.0f);
    float e = __expf(z);
    return v * __builtin_amdgcn_rcpf(1.0f + e);
}

// ---------------- Kernel 0: zero attn scratch (ws is poisoned 0xAA) --------
__global__ void attn_zero_kernel(float* __restrict__ attn) {
    int i = blockIdx.x * 256 + threadIdx.x;
    if (i < 81 * 81) attn[i] = 0.0f;
}

// ---------------- Kernel 1: block-sparse attn = (w1^T . w2^T) .* mask ------
// CH 108 -> 54: grid 243 -> 486 blocks (was <1 block/CU, latency-bound on
// its serial stage->compute; more blocks = more latency hiding). 2916=54*54.
#define CH 54

__global__ __launch_bounds__(256) void bfly_attn_kernel(
        const float* __restrict__ w1,   // [2916, 729]
        const float* __restrict__ w2,   // [729, 2916]
        float* __restrict__ attn)       // [81*81], pre-zeroed
{
    const int G1    = blockIdx.x % 9;
    const int d0    = (blockIdx.x / 9) * CH;
    const int tid   = threadIdx.x;

    __shared__ float ws1[CH * 81];      // [dl][c]   17496 B
    __shared__ float ws2[81 * CH];      // [tl][dl]  17496 B

    for (int i = tid; i < CH * 81; i += 256) {
        int dl = i / 81, c = i % 81;
        ws1[i] = w1[(d0 + dl) * 729 + 81 * G1 + c];
    }
    for (int i = tid; i < 81 * CH; i += 256) {
        int tl = i / CH, dl = i % CH;
        ws2[i] = w2[(81 * G1 + tl) * 2916 + d0 + dl];
    }
    __syncthreads();

    if (tid < 243) {
        const int G2  = tid / 27;
        const int ls  = (tid % 27) / 3;
        const int lt0 = (tid % 3) * 3;
        const int s_l = 27 * (ls / 3) + 3 * G2 + (ls % 3);
        int t_l[3];
        #pragma unroll
        for (int j = 0; j < 3; ++j) {
            int lt = lt0 + j;
            t_l[j] = 27 * (lt / 3) + 3 * G2 + (lt % 3);
        }

        float a0 = 0.f, a1 = 0.f, a2 = 0.f;
        for (int dl = 0; dl < CH; ++dl) {
            float av = ws1[dl * 81 + s_l];
            a0 = fmaf(av, ws2[t_l[0] * CH + dl], a0);
            a1 = fmaf(av, ws2[t_l[1] * CH + dl], a1);
            a2 = fmaf(av, ws2[t_l[2] * CH + dl], a2);
        }

        const int g = 9 * G1 + G2;
        float* dst = &attn[g * 81 + ls * 9 + lt0];
        atomicAdd(dst + 0, a0);
        atomicAdd(dst + 1, a1);
        atomicAdd(dst + 2, a2);
    }
}

// ---------------- Kernel 2: out = gelu(x @ attn_blocksparse + b2) ----------
// Register-resident double-buffered pipeline, no LDS, no barriers.
//   Block owns 32 rows = 8 chunks of 4. Named buffers xa/xb (all indices
//   compile-time -> registers, never scratch). Per chunk: issue next
//   chunk's 12 dwordx3 loads, sched_barrier(0x7) pins them above the
//   compute, compute+store current chunk (compiler emits counted vmcnt:
//   waits xa's loads, leaves xb's 12 in flight).
#define RPC 4            // rows per chunk
#define CPB 8            // chunks per block -> 32 rows
#define NBLK 1536        // 1536 * 32 = 49152 rows

struct f3 { float x, y, z; };   // 12 B, 4 B aligned -> dwordx3

__global__ __launch_bounds__(256, 4) void bfly_mlp_kernel(
        const float* __restrict__ xg,    // [49152, 729] fp32
        const float* __restrict__ attn,  // [81*81] fp32 (ws)
        const float* __restrict__ b2g,   // [729] fp32
        float* __restrict__ outg)        // [49152, 729] fp32
{
    const int tid = threadIdx.x;
    if (tid >= 243) return;              // no barriers -> early exit safe

    const int t1 = tid / 9;              // 0..26
    const int G2 = tid % 9;              // 0..8
    const int G1 = t1 / 3;
    const int li = t1 % 3;
    const int tb = 3 * tid;              // contiguous output triplet
    const int sb = 81 * G1 + 3 * G2;     // x column base (3 triplets @ 27)
    const int g  = 9 * G1 + G2;

    float a[9][3], bias[3];
    #pragma unroll
    for (int ls = 0; ls < 9; ++ls) {
        f3 v = *reinterpret_cast<const f3*>(&attn[g * 81 + ls * 9 + 3 * li]);
        a[ls][0] = v.x; a[ls][1] = v.y; a[ls][2] = v.z;
    }
    {
        f3 v = *reinterpret_cast<const f3*>(&b2g[tb]);
        bias[0] = v.x; bias[1] = v.y; bias[2] = v.z;
    }

    const long long rowbase = (long long)blockIdx.x * (RPC * CPB);
    const float* __restrict__ xbase = xg + rowbase * 729 + sb;
    float* __restrict__ obase       = outg + rowbase * 729 + tb;

    float xa[RPC][9], xb[RPC][9];

    auto load_chunk = [&](int c, float (&dst)[RPC][9]) {
        #pragma unroll
        for (int r = 0; r < RPC; ++r) {
            const float* xr = xbase + (c * RPC + r) * 729;
            f3 v0 = *reinterpret_cast<const f3*>(xr);
            f3 v1 = *reinterpret_cast<const f3*>(xr + 27);
            f3 v2 = *reinterpret_cast<const f3*>(xr + 54);
            dst[r][0] = v0.x; dst[r][1] = v0.y; dst[r][2] = v0.z;
            dst[r][3] = v1.x; dst[r][4] = v1.y; dst[r][5] = v1.z;
            dst[r][6] = v2.x; dst[r][7] = v2.y; dst[r][8] = v2.z;
        }
    };

    auto comp_store = [&](int c, const float (&src)[RPC][9]) {
        #pragma unroll
        for (int r = 0; r < RPC; ++r) {
            float acc0 = bias[0], acc1 = bias[1], acc2 = bias[2];
            #pragma unroll
            for (int ls = 0; ls < 9; ++ls) {
                acc0 = fmaf(src[r][ls], a[ls][0], acc0);
                acc1 = fmaf(src[r][ls], a[ls][1], acc1);
                acc2 = fmaf(src[r][ls], a[ls][2], acc2);
            }
            f3 o; o.x = gelu_f(acc0); o.y = gelu_f(acc1); o.z = gelu_f(acc2);
            *reinterpret_cast<f3*>(obase + (c * RPC + r) * 729) = o;
        }
    };

    // Prologue: chunk 0 in flight.
    load_chunk(0, xa);
    __builtin_amdgcn_sched_barrier(0x7);   // ALU may cross; VMEM pinned

    #pragma unroll
    for (int c = 0; c < CPB; c += 2) {
        // Prefetch c+1 into xb; pin above the xa-compute that follows.
        load_chunk(c + 1, xb);
        __builtin_amdgcn_sched_barrier(0x7);
        comp_store(c, xa);                 // waits xa only; xb stays in flight

        if (c + 2 < CPB) {
            load_chunk(c + 2, xa);         // prefetch c+2 into xa
            __builtin_amdgcn_sched_barrier(0x7);
        }
        comp_store(c + 1, xb);             // waits xb only; xa in flight
    }
}

extern "C" void kernel_launch(void* const* d_in, const int* in_sizes, int n_in,
                              void* d_out, int out_size, void* d_ws, size_t ws_size,
                              hipStream_t stream) {
    const float* x  = (const float*)d_in[0];  // [64,768,729]
    const float* w1 = (const float*)d_in[1];  // [2916,729]
    const float* w2 = (const float*)d_in[2];  // [729,2916]
    const float* b2 = (const float*)d_in[3];  // [729]
    // d_in[4] = sparse_mask: static butterfly structure, never read.

    float* attn = (float*)d_ws;  // 26244 B scratch

    attn_zero_kernel<<<26, 256, 0, stream>>>(attn);
    bfly_attn_kernel<<<9 * (2916 / CH), 256, 0, stream>>>(w1, w2, attn);

    bfly_mlp_kernel<<<NBLK, 256, 0, stream>>>(x, attn, b2, (float*)d_out);
}

// Round 9
// 275.115 us; speedup vs baseline: 1.0728x; 1.0728x over previous
//
#include <hip/hip_runtime.h>
#include <hip/hip_bf16.h>

// Butterfly structure (BASE=3, FACTOR=0, n=27):
//   mask[s,t] != 0  iff  floor(s1/3)==floor(t1/3) && floor(s2/3)==floor(t2/3),
//   s = 27*s1 + s2.  81 groups g=(G1,G2); group members: 81*G1 + 27*i + 3*G2 + j.
//   attn packed: attn[g*81 + ls*9 + lt], g = 9*G1+G2, ls/lt = 3i+j.
// Dtypes: inputs fp32, output fp32.
//
// Cost model (solved r8): total = mlp + ~190 us constant (2x 86us harness
// poison-fills + attn + zero + gaps). Coefficient on mlp is 1.
// attn: CH=54 cost ~8 us vs CH=108 (doubled atomics) — reverted to 108.
//
// The 86-us wall: every clean variant (r0 LDS-stage 88, r4 direct 90,
// r5 24-deep burst 86.8, r6 all-coalesced 85.4, r7 dbuf 86.6) moves the
// logical 286 MB at 3.3-3.5 TB/s. Write-only fill: 6.6 TB/s in-run.
// Immune to: occupancy (26-55%), ILP depth, granularity, coalescing, LDS,
// pipelining attempts (compiler collapses reg pipelines: r7 VGPR 44,
// r8 VGPR 64 vs required >100). Model: per-CU read-miss concurrency
// (MSHR) limit: ~4400 line-misses/CU x 400-900cy / ~32 trackers = 70-90us.
// This round (last untested lever): global_load_lds DMA staging — the
// direct-to-LDS request path; r1/r2 (its only users) were the only kernels
// to exceed 3.5 TB/s physical. Exact r0 structure otherwise (A/B vs 88us).

__device__ __forceinline__ float gelu_f(float v) {
    // tanh-form gelu; |err| < ~7e-4, threshold 1.44e-2 (measured absmax 3.9e-3).
    float u2 = v * v;
    float z = -1.5957691216f * v * fmaf(0.044715f, u2, 1.0f);
    float e = __expf(z);
    return v * __builtin_amdgcn_rcpf(1.0f + e);
}

// ---------------- Kernel 0: zero attn scratch (ws is poisoned 0xAA) --------
__global__ void attn_zero_kernel(float* __restrict__ attn) {
    int i = blockIdx.x * 256 + threadIdx.x;
    if (i < 81 * 81) attn[i] = 0.0f;
}

// ---------------- Kernel 1: block-sparse attn = (w1^T . w2^T) .* mask ------
// CH=108 (r0-proven; CH=54 regressed total by ~8 us in r8).
#define CH 108   // 27 chunks * 108 = 2916

__global__ __launch_bounds__(256) void bfly_attn_kernel(
        const float* __restrict__ w1,   // [2916, 729]
        const float* __restrict__ w2,   // [729, 2916]
        float* __restrict__ attn)       // [81*81], pre-zeroed
{
    const int G1    = blockIdx.x % 9;
    const int d0    = (blockIdx.x / 9) * CH;
    const int tid   = threadIdx.x;

    __shared__ float ws1[CH * 81];      // [dl][c]   34992 B
    __shared__ float ws2[81 * CH];      // [tl][dl]  34992 B

    for (int i = tid; i < CH * 81; i += 256) {
        int dl = i / 81, c = i % 81;
        ws1[i] = w1[(d0 + dl) * 729 + 81 * G1 + c];
    }
    for (int i = tid; i < 81 * CH; i += 256) {
        int tl = i / CH, dl = i % CH;
        ws2[i] = w2[(81 * G1 + tl) * 2916 + d0 + dl];
    }
    __syncthreads();

    if (tid < 243) {
        const int G2  = tid / 27;
        const int ls  = (tid % 27) / 3;
        const int lt0 = (tid % 3) * 3;
        const int s_l = 27 * (ls / 3) + 3 * G2 + (ls % 3);
        int t_l[3];
        #pragma unroll
        for (int j = 0; j < 3; ++j) {
            int lt = lt0 + j;
            t_l[j] = 27 * (lt / 3) + 3 * G2 + (lt % 3);
        }

        float a0 = 0.f, a1 = 0.f, a2 = 0.f;
        for (int dl = 0; dl < CH; ++dl) {
            float av = ws1[dl * 81 + s_l];
            a0 = fmaf(av, ws2[t_l[0] * CH + dl], a0);
            a1 = fmaf(av, ws2[t_l[1] * CH + dl], a1);
            a2 = fmaf(av, ws2[t_l[2] * CH + dl], a2);
        }

        const int g = 9 * G1 + G2;
        float* dst = &attn[g * 81 + ls * 9 + lt0];
        atomicAdd(dst + 0, a0);
        atomicAdd(dst + 1, a1);
        atomicAdd(dst + 2, a2);
    }
}

// ---------------- Kernel 2: out = gelu(x @ attn_blocksparse + b2) ----------
// r0 structure exactly (short-lived 6144 blocks, ROWS=8, one staging
// barrier, direct scatter stores) with ONE change: staging goes through
// the global_load_lds DMA path (16 B/lane, no VGPR round-trip) instead of
// uint4 register copies. Single-variable A/B against r0's 88 us.
#define ROWS 8
#define NV4  (ROWS * 729 / 4)   // 1458 uint4 per tile

struct f3 { float x, y, z; };   // 12 B, 4 B aligned -> dwordx3

__global__ __launch_bounds__(256) void bfly_mlp_kernel(
        const float* __restrict__ xg,    // [49152, 729] fp32
        const float* __restrict__ attn,  // [81*81] fp32 (ws)
        const float* __restrict__ b2g,   // [729] fp32
        float* __restrict__ outg)        // [49152, 729] fp32
{
    __shared__ float xs[ROWS * 729];     // 23328 B -> 6 blocks/CU

    const int tid = threadIdx.x;
    const bool active = (tid < 243);

    // Weights hoisted above staging: their global latency overlaps the DMA.
    float a[9][3], bias[3];
    int tb = 0, sb = 0;
    if (active) {
        const int t1 = tid / 9;           // 0..26
        const int G2 = tid % 9;           // 0..8
        const int G1 = t1 / 3;
        const int li = t1 % 3;
        tb = 3 * tid;                     // contiguous output triplet
        sb = 81 * G1 + 3 * G2;            // x column base (3 triplets @ 27)
        const int g  = 9 * G1 + G2;
        #pragma unroll
        for (int ls = 0; ls < 9; ++ls) {
            f3 v = *reinterpret_cast<const f3*>(&attn[g * 81 + ls * 9 + 3 * li]);
            a[ls][0] = v.x; a[ls][1] = v.y; a[ls][2] = v.z;
        }
        f3 v = *reinterpret_cast<const f3*>(&b2g[tb]);
        bias[0] = v.x; bias[1] = v.y; bias[2] = v.z;
    }

    const long long rowbase = (long long)blockIdx.x * ROWS;

    // ---- Stage via global->LDS DMA: 1458 x 16 B, wave-uniform base +
    // lane*16 dest (r1-proven addressing, refcheck-passed). ----
    {
        const uint4* __restrict__ src = (const uint4*)(xg + rowbase * 729);
        #pragma unroll
        for (int k = 0; k < 6; ++k) {
            const int i = tid + k * 256;
            if (i < NV4) {
                __builtin_amdgcn_global_load_lds(
                    (const __attribute__((address_space(1))) void*)(src + i),
                    (__attribute__((address_space(3))) void*)(&xs[i * 4]),
                    16, 0, 0);
            }
        }
    }
    __syncthreads();   // drains vmcnt(0) + lgkmcnt(0), DMA visible block-wide

    if (active) {
        #pragma unroll 2
        for (int r = 0; r < ROWS; ++r) {
            const float* xr = &xs[r * 729 + sb];
            float xv[9];
            #pragma unroll
            for (int i2 = 0; i2 < 3; ++i2)
                #pragma unroll
                for (int j2 = 0; j2 < 3; ++j2)
                    xv[3 * i2 + j2] = xr[27 * i2 + j2];

            float acc0 = bias[0], acc1 = bias[1], acc2 = bias[2];
            #pragma unroll
            for (int ls = 0; ls < 9; ++ls) {
                acc0 = fmaf(xv[ls], a[ls][0], acc0);
                acc1 = fmaf(xv[ls], a[ls][1], acc1);
                acc2 = fmaf(xv[ls], a[ls][2], acc2);
            }

            f3 o; o.x = gelu_f(acc0); o.y = gelu_f(acc1); o.z = gelu_f(acc2);
            *reinterpret_cast<f3*>(&outg[(rowbase + r) * 729 + tb]) = o;
        }
    }
}

extern "C" void kernel_launch(void* const* d_in, const int* in_sizes, int n_in,
                              void* d_out, int out_size, void* d_ws, size_t ws_size,
                              hipStream_t stream) {
    const float* x  = (const float*)d_in[0];  // [64,768,729]
    const float* w1 = (const float*)d_in[1];  // [2916,729]
    const float* w2 = (const float*)d_in[2];  // [729,2916]
    const float* b2 = (const float*)d_in[3];  // [729]
    // d_in[4] = sparse_mask: static butterfly structure, never read.

    float* attn = (float*)d_ws;  // 26244 B scratch

    attn_zero_kernel<<<26, 256, 0, stream>>>(attn);
    bfly_attn_kernel<<<9 * 27, 256, 0, stream>>>(w1, w2, attn);

    const int n_rows = 64 * 768;             // 49152
    bfly_mlp_kernel<<<n_rows / ROWS, 256, 0, stream>>>(
        x, attn, b2, (float*)d_out);
}